// Round 1
// baseline (4194.850 us; speedup 1.0000x reference)
//
#include <hip/hip_runtime.h>
#include <math.h>

// Problem constants (fixed by the reference)
#define Bn   4
#define Nn   2048
#define Kn   30
#define Hn   128
#define En   128
#define IN1  384            // E + 2H
#define NNODE (Bn * Nn)     // 8192

__device__ __forceinline__ float gelu_f(float x) {
    // exact (erf) GELU, matches jax.nn.gelu(approximate=False)
    return 0.5f * x * (1.0f + erff(x * 0.7071067811865476f));
}

__device__ __forceinline__ float dot4(float4 a, float4 b) {
    return a.x * b.x + a.y * b.y + a.z * b.z + a.w * b.w;
}

// Accumulate 15 rows (k = kg*15 + r) against one weight row segment of length Hn.
// src is an LDS matrix [Kn][Hn]; all lanes of a wave read the SAME LDS address
// (broadcast, conflict-free); each lane owns one output channel o.
__device__ __forceinline__ void gemm_seg(const float* __restrict__ wrow,
                                         const float* __restrict__ src,
                                         int kg, float acc[15]) {
    for (int i = 0; i < Hn; i += 4) {
        float4 wv = *(const float4*)(wrow + i);
        #pragma unroll
        for (int r = 0; r < 15; r++)
            acc[r] += dot4(wv, *(const float4*)(src + (kg * 15 + r) * Hn + i));
    }
}

// ---------------------------------------------------------------------------
// Kernel A: node update (message MLP + mean over K + LN1 + FFN + LN2 + mask_V)
// One block (256 threads) per node. Thread t: o = t&127 (output channel),
// kg = t>>7 (edge-row half: k = kg*15 + r).
// ---------------------------------------------------------------------------
__global__ __launch_bounds__(256) void node_update_kernel(
    const float* __restrict__ h_V, const float* __restrict__ h_E,
    const int*   __restrict__ E_idx,
    const float* __restrict__ mask_V, const float* __restrict__ mask_attend,
    const float* __restrict__ W1_w, const float* __restrict__ W1_b,
    const float* __restrict__ W2_w, const float* __restrict__ W2_b,
    const float* __restrict__ W3_w, const float* __restrict__ W3_b,
    const float* __restrict__ Win_w, const float* __restrict__ Win_b,
    const float* __restrict__ Wout_w, const float* __restrict__ Wout_b,
    const float* __restrict__ g1, const float* __restrict__ b1v,
    const float* __restrict__ g2, const float* __restrict__ b2v,
    float* __restrict__ hV_out)
{
    __shared__ __align__(16) float sXS[Hn];        // self row (stays live)
    __shared__ __align__(16) float sXE[Kn * Hn];   // h_E rows; dead after GEMM1 ->
                                                   //  tbuf[512] | red[256] | hv1[128]
    __shared__ __align__(16) float sXN[Kn * Hn];   // neighbor rows; dead after GEMM1 -> Y2
    __shared__ __align__(16) float sY1[Kn * Hn];   // GEMM1 output
    __shared__ float sStats[4];

    const int p   = blockIdx.x;      // node id = b*Nn + n
    const int b   = p >> 11;         // / Nn
    const int tid = threadIdx.x;
    const int o   = tid & 127;
    const int kg  = tid >> 7;

    // ---- stage inputs into LDS ----
    {
        const float4* src = (const float4*)(h_E + (size_t)p * Kn * En);
        float4* dst = (float4*)sXE;
        for (int i = tid; i < Kn * Hn / 4; i += 256) dst[i] = src[i];
    }
    if (tid < Hn / 4)
        ((float4*)sXS)[tid] = ((const float4*)(h_V + (size_t)p * Hn))[tid];
    {
        const int c = tid & 31;
        for (int k = tid >> 5; k < Kn; k += 8) {
            int idx = E_idx[p * Kn + k];
            const float4* src = (const float4*)(h_V + ((size_t)b * Nn + idx) * Hn);
            ((float4*)(sXN + k * Hn))[c] = src[c];
        }
    }
    __syncthreads();

    float acc[15];

    // ---- GEMM1: [30,384] x W1^T -> GELU -> Y1 [30,128] ----
    {
        const float* w = W1_w + o * IN1;
        float accS = 0.f;                       // k-invariant self segment
        for (int i = 0; i < Hn; i += 4)
            accS += dot4(*(const float4*)(w + i), *(const float4*)(sXS + i));
        #pragma unroll
        for (int r = 0; r < 15; r++) acc[r] = 0.f;
        gemm_seg(w + Hn,     sXE, kg, acc);     // h_E segment
        gemm_seg(w + 2 * Hn, sXN, kg, acc);     // neighbor segment
        float bias = W1_b[o];
        #pragma unroll
        for (int r = 0; r < 15; r++)
            sY1[(kg * 15 + r) * Hn + o] = gelu_f(accS + acc[r] + bias);
    }
    __syncthreads();

    // ---- GEMM2: Y1 x W2^T -> GELU -> Y2 (aliases sXN) ----
    {
        const float* w = W2_w + o * Hn;
        #pragma unroll
        for (int r = 0; r < 15; r++) acc[r] = 0.f;
        gemm_seg(w, sY1, kg, acc);
        float bias = W2_b[o];
        #pragma unroll
        for (int r = 0; r < 15; r++)
            sXN[(kg * 15 + r) * Hn + o] = gelu_f(acc[r] + bias);
    }
    __syncthreads();

    // ---- GEMM3: Y2 x W3^T, mask_attend-weighted partial sum over k ----
    float* red = sXE + 512;   // 2*128 partials (sXE dead)
    {
        const float* w = W3_w + o * Hn;
        #pragma unroll
        for (int r = 0; r < 15; r++) acc[r] = 0.f;
        gemm_seg(w, sXN, kg, acc);
        float bias = W3_b[o];
        float part = 0.f;
        #pragma unroll
        for (int r = 0; r < 15; r++) {
            int k = kg * 15 + r;
            part += mask_attend[p * Kn + k] * (acc[r] + bias);
        }
        red[kg * 128 + o] = part;
    }
    __syncthreads();

    // ---- dh, residual, LN1 ----
    float* xrow = sXE + 512;  // reuse red[0] slots to hold x
    if (tid < Hn) {
        float dh = (red[tid] + red[128 + tid]) * (1.0f / 30.0f);
        xrow[tid] = sXS[tid] + dh;
    }
    __syncthreads();
    if (tid < 64) {
        float x0 = xrow[tid], x1 = xrow[tid + 64];
        float s = x0 + x1, q = x0 * x0 + x1 * x1;
        #pragma unroll
        for (int off = 32; off > 0; off >>= 1) {
            s += __shfl_down(s, off); q += __shfl_down(q, off);
        }
        if (tid == 0) {
            float mean = s * (1.0f / 128.0f);
            float var  = q * (1.0f / 128.0f) - mean * mean;
            sStats[0] = mean; sStats[1] = rsqrtf(var + 1e-5f);
        }
    }
    __syncthreads();
    float* hv1 = sXE + 768;   // 128 floats
    if (tid < Hn) {
        hv1[tid] = (xrow[tid] - sStats[0]) * sStats[1] * g1[tid] + b1v[tid];
    }
    __syncthreads();

    // ---- FFN: t = GELU(Win x hv1 + b), 512 wide ----
    float* tbuf = sXE;        // 512 floats
    {
        float a0 = Win_b[tid], a1 = Win_b[tid + 256];
        const float* w0 = Win_w + tid * Hn;
        const float* w1 = Win_w + (tid + 256) * Hn;
        for (int i = 0; i < Hn; i += 4) {
            float4 x = *(const float4*)(hv1 + i);
            a0 += dot4(*(const float4*)(w0 + i), x);
            a1 += dot4(*(const float4*)(w1 + i), x);
        }
        tbuf[tid]       = gelu_f(a0);
        tbuf[tid + 256] = gelu_f(a1);
    }
    __syncthreads();

    // ---- dh2 = Wout x t + b, residual ----
    if (tid < Hn) {
        float a = Wout_b[tid];
        const float* w = Wout_w + tid * 512;
        for (int i = 0; i < 512; i += 4)
            a += dot4(*(const float4*)(w + i), *(const float4*)(tbuf + i));
        xrow[tid] = hv1[tid] + a;
    }
    __syncthreads();

    // ---- LN2 + mask_V + store ----
    if (tid < 64) {
        float x0 = xrow[tid], x1 = xrow[tid + 64];
        float s = x0 + x1, q = x0 * x0 + x1 * x1;
        #pragma unroll
        for (int off = 32; off > 0; off >>= 1) {
            s += __shfl_down(s, off); q += __shfl_down(q, off);
        }
        if (tid == 0) {
            float mean = s * (1.0f / 128.0f);
            float var  = q * (1.0f / 128.0f) - mean * mean;
            sStats[2] = mean; sStats[3] = rsqrtf(var + 1e-5f);
        }
    }
    __syncthreads();
    if (tid < Hn) {
        float y = ((xrow[tid] - sStats[2]) * sStats[3] * g2[tid] + b2v[tid]) * mask_V[p];
        hV_out[(size_t)p * Hn + tid] = y;
    }
}

// ---------------------------------------------------------------------------
// Kernel B: edge update. Reads the UPDATED h_V (written by kernel A into
// d_out), same 3-GEMM skeleton, then per-edge-row LayerNorm.
// ---------------------------------------------------------------------------
__global__ __launch_bounds__(256) void edge_update_kernel(
    const float* __restrict__ hV_new, const float* __restrict__ h_E,
    const int*   __restrict__ E_idx,
    const float* __restrict__ W11_w, const float* __restrict__ W11_b,
    const float* __restrict__ W12_w, const float* __restrict__ W12_b,
    const float* __restrict__ W13_w, const float* __restrict__ W13_b,
    const float* __restrict__ g3, const float* __restrict__ b3v,
    float* __restrict__ hE_out)
{
    __shared__ __align__(16) float sXS[Hn];
    __shared__ __align__(16) float sXE[Kn * Hn];   // h_E rows — live to the end (residual)
    __shared__ __align__(16) float sXN[Kn * Hn];   // neighbors -> Y2 after GEMM1
    __shared__ __align__(16) float sY1[Kn * Hn];   // Y1 -> M (GEMM3 out)

    const int p   = blockIdx.x;
    const int b   = p >> 11;
    const int tid = threadIdx.x;
    const int o   = tid & 127;
    const int kg  = tid >> 7;

    {
        const float4* src = (const float4*)(h_E + (size_t)p * Kn * En);
        float4* dst = (float4*)sXE;
        for (int i = tid; i < Kn * Hn / 4; i += 256) dst[i] = src[i];
    }
    if (tid < Hn / 4)
        ((float4*)sXS)[tid] = ((const float4*)(hV_new + (size_t)p * Hn))[tid];
    {
        const int c = tid & 31;
        for (int k = tid >> 5; k < Kn; k += 8) {
            int idx = E_idx[p * Kn + k];
            const float4* src = (const float4*)(hV_new + ((size_t)b * Nn + idx) * Hn);
            ((float4*)(sXN + k * Hn))[c] = src[c];
        }
    }
    __syncthreads();

    float acc[15];

    // GEMM1 (W11) -> GELU -> Y1
    {
        const float* w = W11_w + o * IN1;
        float accS = 0.f;
        for (int i = 0; i < Hn; i += 4)
            accS += dot4(*(const float4*)(w + i), *(const float4*)(sXS + i));
        #pragma unroll
        for (int r = 0; r < 15; r++) acc[r] = 0.f;
        gemm_seg(w + Hn,     sXE, kg, acc);
        gemm_seg(w + 2 * Hn, sXN, kg, acc);
        float bias = W11_b[o];
        #pragma unroll
        for (int r = 0; r < 15; r++)
            sY1[(kg * 15 + r) * Hn + o] = gelu_f(accS + acc[r] + bias);
    }
    __syncthreads();

    // GEMM2 (W12) -> GELU -> Y2 (aliases sXN)
    {
        const float* w = W12_w + o * Hn;
        #pragma unroll
        for (int r = 0; r < 15; r++) acc[r] = 0.f;
        gemm_seg(w, sY1, kg, acc);
        float bias = W12_b[o];
        #pragma unroll
        for (int r = 0; r < 15; r++)
            sXN[(kg * 15 + r) * Hn + o] = gelu_f(acc[r] + bias);
    }
    __syncthreads();

    // GEMM3 (W13, no activation) -> M (aliases sY1)
    {
        const float* w = W13_w + o * Hn;
        #pragma unroll
        for (int r = 0; r < 15; r++) acc[r] = 0.f;
        gemm_seg(w, sXN, kg, acc);
        float bias = W13_b[o];
        #pragma unroll
        for (int r = 0; r < 15; r++)
            sY1[(kg * 15 + r) * Hn + o] = acc[r] + bias;
    }
    __syncthreads();

    // Per-row LN over E=128: one wave handles rows k = w, w+4, ...
    {
        const int lane = tid & 63;
        const int wv   = tid >> 6;     // wave id, 0..3
        for (int k = wv; k < Kn; k += 4) {
            float x0 = sXE[k * Hn + lane]      + sY1[k * Hn + lane];
            float x1 = sXE[k * Hn + lane + 64] + sY1[k * Hn + lane + 64];
            float s = x0 + x1, q = x0 * x0 + x1 * x1;
            #pragma unroll
            for (int off = 32; off > 0; off >>= 1) {
                s += __shfl_down(s, off); q += __shfl_down(q, off);
            }
            s = __shfl(s, 0); q = __shfl(q, 0);
            float mean = s * (1.0f / 128.0f);
            float inv  = rsqrtf(q * (1.0f / 128.0f) - mean * mean + 1e-5f);
            float* outp = hE_out + ((size_t)p * Kn + k) * En;
            outp[lane]      = (x0 - mean) * inv * g3[lane]      + b3v[lane];
            outp[lane + 64] = (x1 - mean) * inv * g3[lane + 64] + b3v[lane + 64];
        }
    }
}

extern "C" void kernel_launch(void* const* d_in, const int* in_sizes, int n_in,
                              void* d_out, int out_size, void* d_ws, size_t ws_size,
                              hipStream_t stream)
{
    const float* h_V         = (const float*)d_in[0];
    const float* h_E         = (const float*)d_in[1];
    const int*   E_idx       = (const int*)  d_in[2];
    const float* mask_V      = (const float*)d_in[3];
    const float* mask_attend = (const float*)d_in[4];
    const float* W1_w  = (const float*)d_in[5];
    const float* W1_b  = (const float*)d_in[6];
    const float* W2_w  = (const float*)d_in[7];
    const float* W2_b  = (const float*)d_in[8];
    const float* W3_w  = (const float*)d_in[9];
    const float* W3_b  = (const float*)d_in[10];
    const float* W11_w = (const float*)d_in[11];
    const float* W11_b = (const float*)d_in[12];
    const float* W12_w = (const float*)d_in[13];
    const float* W12_b = (const float*)d_in[14];
    const float* W13_w = (const float*)d_in[15];
    const float* W13_b = (const float*)d_in[16];
    const float* Win_w  = (const float*)d_in[17];
    const float* Win_b  = (const float*)d_in[18];
    const float* Wout_w = (const float*)d_in[19];
    const float* Wout_b = (const float*)d_in[20];
    const float* g1 = (const float*)d_in[21];
    const float* b1 = (const float*)d_in[22];
    const float* g2 = (const float*)d_in[23];
    const float* b2 = (const float*)d_in[24];
    const float* g3 = (const float*)d_in[25];
    const float* b3 = (const float*)d_in[26];

    float* out    = (float*)d_out;
    float* hV_out = out;                              // [B,N,H]
    float* hE_out = out + (size_t)Bn * Nn * Hn;       // [B,N,K,E]

    node_update_kernel<<<NNODE, 256, 0, stream>>>(
        h_V, h_E, E_idx, mask_V, mask_attend,
        W1_w, W1_b, W2_w, W2_b, W3_w, W3_b,
        Win_w, Win_b, Wout_w, Wout_b,
        g1, b1, g2, b2, hV_out);

    edge_update_kernel<<<NNODE, 256, 0, stream>>>(
        hV_out, h_E, E_idx,
        W11_w, W11_b, W12_w, W12_b, W13_w, W13_b,
        g3, b3, hE_out);
}

// Round 2
// 885.358 us; speedup vs baseline: 4.7380x; 4.7380x over previous
//
#include <hip/hip_runtime.h>
#include <math.h>

// Problem constants
#define Kn    30
#define Hn    128
#define NB    2048          // nodes per batch
#define XS    392           // X row stride (384 + 8 pad), 16B-group stride 49 (odd)
#define YS    136           // Y row stride (128 + 8 pad), 16B-group stride 17 (odd)
#define TBS   520           // FFN hidden row stride (512 + 8 pad), groups 65 (odd)

// ws layout (bf16 elems)
#define OFF_W1    0
#define OFF_W2    49152
#define OFF_W3    65536
#define OFF_W11   81920
#define OFF_W12   131072
#define OFF_W13   147456
#define OFF_WIN   163840
#define OFF_WOUT  229376
#define W_TOTAL   294912

typedef __attribute__((ext_vector_type(8)))  short bh8;
typedef __attribute__((ext_vector_type(4)))  short bh4;
typedef __attribute__((ext_vector_type(16))) float fx16;

__device__ __forceinline__ unsigned short f2bf(float f) {
    unsigned int u = __float_as_uint(f);
    u += 0x7fffu + ((u >> 16) & 1u);        // RNE
    return (unsigned short)(u >> 16);
}
__device__ __forceinline__ float bf2f(unsigned short h) {
    return __uint_as_float(((unsigned int)h) << 16);
}
__device__ __forceinline__ float gelu_f(float x) {
    return 0.5f * x * (1.0f + erff(x * 0.7071067811865476f));
}
__device__ __forceinline__ fx16 mfma_bf16(bh8 a, bh8 b, fx16 c) {
    return __builtin_amdgcn_mfma_f32_32x32x16_bf16(a, b, c, 0, 0, 0);
}
__device__ __forceinline__ void st_bf4(unsigned short* dst, float4 v) {
    bh4 t;
    t.x = (short)f2bf(v.x); t.y = (short)f2bf(v.y);
    t.z = (short)f2bf(v.z); t.w = (short)f2bf(v.w);
    *(bh4*)dst = t;                          // ds_write_b64
}

// K-loop: one A row-tile (32 rows) x two B n-tiles. aBase/b0/b1 pre-offset by
// lane: A row = rowBase + (lane&31), k-offset (lane>>5)*8; B row = ncol.
__device__ __forceinline__ void gemm_pair(const unsigned short* __restrict__ aBase,
                                          const unsigned short* __restrict__ b0,
                                          const unsigned short* __restrict__ b1,
                                          int ksteps, fx16& acc0, fx16& acc1) {
    for (int ks = 0; ks < ksteps; ks++) {
        bh8 a  = *(const bh8*)(aBase + ks * 16);
        bh8 w0 = *(const bh8*)(b0 + ks * 16);
        bh8 w1 = *(const bh8*)(b1 + ks * 16);
        acc0 = mfma_bf16(a, w0, acc0);
        acc1 = mfma_bf16(a, w1, acc1);
    }
}

// C-layout (verified m74/m101): col = lane&31, row = (reg&3)+8*(reg>>2)+4*(lane>>5)
__device__ __forceinline__ void epi_gelu(const fx16& ac, int colBase, int rowBase,
                                         const float* __restrict__ bias,
                                         unsigned short* __restrict__ dst, int lane) {
    int col = colBase + (lane & 31);
    float b = bias[col];
    int ro = rowBase + 4 * (lane >> 5);
    #pragma unroll
    for (int r = 0; r < 16; r++) {
        int row = ro + (r & 3) + 8 * (r >> 2);
        dst[row * YS + col] = f2bf(gelu_f(ac[r] + b));
    }
}
__device__ __forceinline__ void epi_plain(const fx16& ac, int colBase, int rowBase,
                                          const float* __restrict__ bias,
                                          unsigned short* __restrict__ dst, int lane) {
    int col = colBase + (lane & 31);
    float b = bias[col];
    int ro = rowBase + 4 * (lane >> 5);
    #pragma unroll
    for (int r = 0; r < 16; r++) {
        int row = ro + (r & 3) + 8 * (r >> 2);
        dst[row * YS + col] = f2bf(ac[r] + b);
    }
}

// ---------------------------------------------------------------------------
// prep: fp32 -> bf16 weights into workspace (runs every launch; ws re-poisoned)
// ---------------------------------------------------------------------------
__global__ __launch_bounds__(256) void prep_weights(
    const float* __restrict__ W1, const float* __restrict__ W2,
    const float* __restrict__ W3, const float* __restrict__ W11,
    const float* __restrict__ W12, const float* __restrict__ W13,
    const float* __restrict__ Win, const float* __restrict__ Wout,
    unsigned short* __restrict__ wsbf) {
    int i = blockIdx.x * 256 + threadIdx.x;
    if (i >= W_TOTAL) return;
    float v;
    if      (i < OFF_W2)   v = W1[i - OFF_W1];
    else if (i < OFF_W3)   v = W2[i - OFF_W2];
    else if (i < OFF_W11)  v = W3[i - OFF_W3];
    else if (i < OFF_W12)  v = W11[i - OFF_W11];
    else if (i < OFF_W13)  v = W12[i - OFF_W12];
    else if (i < OFF_WIN)  v = W13[i - OFF_W13];
    else if (i < OFF_WOUT) v = Win[i - OFF_WIN];
    else                   v = Wout[i - OFF_WOUT];
    wsbf[i] = f2bf(v);
}

// ---------------------------------------------------------------------------
// Kernel A: node update. G=2 nodes/block, M=60 (pad 64), 256 threads = 4 waves.
// Wave w: m-tile = w&1 (rows 32*(w&1)..+31), n-tiles 2*(w>>1), +1 (64 cols).
// ---------------------------------------------------------------------------
__global__ __launch_bounds__(256, 2) void node_update_mfma(
    const float* __restrict__ h_V, const float* __restrict__ h_E,
    const int* __restrict__ E_idx,
    const float* __restrict__ mask_V, const float* __restrict__ mask_attend,
    const unsigned short* __restrict__ wsbf,
    const float* __restrict__ W1_b, const float* __restrict__ W2_b,
    const float* __restrict__ W3_b,
    const float* __restrict__ Win_b, const float* __restrict__ Wout_b,
    const float* __restrict__ g1v, const float* __restrict__ b1v,
    const float* __restrict__ g2v, const float* __restrict__ b2v,
    float* __restrict__ hV_out) {
    __shared__ unsigned short sX[64 * XS];   // [self|h_E|nbr] bf16; aliased by sTB later
    __shared__ unsigned short sY[64 * YS];   // Y1 -> Y2 -> hv1-bf16 (rows 0,1)
    __shared__ float sSelf[256], sHv1[256], sHvX[256], sM2[256];
    __shared__ float sRedP[2][256];          // [m-tile][g*128+col] partial k-sums
    __shared__ float sMask[64];
    __shared__ float sStats[4];

    const int tid = threadIdx.x;
    const int p0  = blockIdx.x * 2;          // first node of the pair
    const int bB  = p0 >> 11;                // batch index
    const unsigned short* W1bf   = wsbf + OFF_W1;
    const unsigned short* W2bf   = wsbf + OFF_W2;
    const unsigned short* W3bf   = wsbf + OFF_W3;
    const unsigned short* Winbf  = wsbf + OFF_WIN;
    const unsigned short* Woutbf = wsbf + OFF_WOUT;

    // ---- staging: 60 rows x 128 per segment, fp32 -> bf16 ----
    for (int i = tid; i < 1920; i += 256) {          // h_E -> cols 128..255
        int r = i >> 5, c4 = (i & 31) << 2;
        float4 v = *(const float4*)(h_E + ((size_t)(p0 * Kn + r)) * Hn + c4);
        st_bf4(sX + r * XS + 128 + c4, v);
    }
    for (int i = tid; i < 1920; i += 256) {          // neighbors -> cols 256..383
        int r = i >> 5, c4 = (i & 31) << 2;
        int idx = E_idx[p0 * Kn + r];
        float4 v = *(const float4*)(h_V + ((size_t)(bB * NB + idx)) * Hn + c4);
        st_bf4(sX + r * XS + 256 + c4, v);
    }
    for (int i = tid; i < 1920; i += 256) {          // self (broadcast) -> cols 0..127
        int r = i >> 5, c4 = (i & 31) << 2;
        float4 v = *(const float4*)(h_V + ((size_t)(p0 + (r >= Kn))) * Hn + c4);
        st_bf4(sX + r * XS + c4, v);
    }
    if (tid < 64) {                                  // fp32 self rows for residual
        int g = tid >> 5, c4 = (tid & 31) << 2;
        *(float4*)(sSelf + g * 128 + c4) =
            *(const float4*)(h_V + (size_t)(p0 + g) * Hn + c4);
    }
    if (tid < 60) sMask[tid] = mask_attend[p0 * Kn + tid];
    __syncthreads();

    const int wid = tid >> 6, lane = tid & 63;
    const int mt = wid & 1, np = wid >> 1;
    const int lane31 = lane & 31, lk = (lane >> 5) << 3;
    const int rowBase = 32 * mt;
    const fx16 zv = {};

    // ---- GEMM1: X[64,384] @ W1^T -> GELU -> Y ----
    fx16 acc0 = zv, acc1 = zv;
    gemm_pair(sX + (rowBase + lane31) * XS + lk,
              W1bf + (64 * np + lane31) * 384 + lk,
              W1bf + (64 * np + 32 + lane31) * 384 + lk, 24, acc0, acc1);
    epi_gelu(acc0, 64 * np,      rowBase, W1_b, sY, lane);
    epi_gelu(acc1, 64 * np + 32, rowBase, W1_b, sY, lane);
    __syncthreads();

    // ---- GEMM2: Y @ W2^T -> GELU -> Y (in place, sync-guarded) ----
    acc0 = zv; acc1 = zv;
    gemm_pair(sY + (rowBase + lane31) * YS + lk,
              W2bf + (64 * np + lane31) * 128 + lk,
              W2bf + (64 * np + 32 + lane31) * 128 + lk, 8, acc0, acc1);
    __syncthreads();
    epi_gelu(acc0, 64 * np,      rowBase, W2_b, sY, lane);
    epi_gelu(acc1, 64 * np + 32, rowBase, W2_b, sY, lane);
    __syncthreads();

    // ---- GEMM3: Y @ W3^T, masked k-reduction in-register ----
    acc0 = zv; acc1 = zv;
    gemm_pair(sY + (rowBase + lane31) * YS + lk,
              W3bf + (64 * np + lane31) * 128 + lk,
              W3bf + (64 * np + 32 + lane31) * 128 + lk, 8, acc0, acc1);
    #pragma unroll
    for (int t = 0; t < 2; t++) {
        const fx16& ac = t ? acc1 : acc0;
        int col = 64 * np + 32 * t + lane31;
        float bias = W3_b[col];
        float s0 = 0.f, s1 = 0.f;
        #pragma unroll
        for (int r = 0; r < 16; r++) {
            int row = rowBase + ((r & 3) + 8 * (r >> 2) + 4 * (lane >> 5));
            if (row < 60) {
                float v = (ac[r] + bias) * sMask[row];
                if (row < Kn) s0 += v; else s1 += v;
            }
        }
        s0 += __shfl_down(s0, 32);               // lanes l,l+32 cover all 32 rows
        s1 += __shfl_down(s1, 32);
        if (lane < 32) { sRedP[mt][col] = s0; sRedP[mt][128 + col] = s1; }
    }
    __syncthreads();                              // also: all GEMM3 reads of sY done

    // ---- dh, residual, LN1 ----
    {
        int g = tid >> 7, c = tid & 127;
        float x = sSelf[g * 128 + c] +
                  (sRedP[0][g * 128 + c] + sRedP[1][g * 128 + c]) * (1.0f / 30.0f);
        sHvX[g * 128 + c] = x;
    }
    __syncthreads();
    if (wid < 2) {
        float x0 = sHvX[wid * 128 + lane], x1 = sHvX[wid * 128 + 64 + lane];
        float s = x0 + x1, q = x0 * x0 + x1 * x1;
        #pragma unroll
        for (int off = 32; off; off >>= 1) { s += __shfl_down(s, off); q += __shfl_down(q, off); }
        if (lane == 0) {
            float mean = s * 0.0078125f;
            sStats[wid * 2] = mean;
            sStats[wid * 2 + 1] = rsqrtf(q * 0.0078125f - mean * mean + 1e-5f);
        }
    }
    __syncthreads();
    {
        int g = tid >> 7, c = tid & 127;
        float hv = (sHvX[g * 128 + c] - sStats[g * 2]) * sStats[g * 2 + 1] * g1v[c] + b1v[c];
        sHv1[g * 128 + c] = hv;
        sY[g * YS + c] = f2bf(hv);               // rows 0,1 of sY = FFN A-matrix
    }
    __syncthreads();

    // ---- FFN-in: [2(pad 32),128] @ Win^T(512x128) -> GELU; rows 2..31 garbage,
    //      confined per-row by MFMA semantics ----
    fx16 f0 = zv, f1 = zv, f2a = zv, f3a = zv;
    {
        const unsigned short* a = sY + lane31 * YS + lk;
        const unsigned short* bw = Winbf + (128 * wid + lane31) * 128 + lk;
        for (int ks = 0; ks < 8; ks++) {
            bh8 a8 = *(const bh8*)(a + ks * 16);
            f0  = mfma_bf16(a8, *(const bh8*)(bw + ks * 16), f0);
            f1  = mfma_bf16(a8, *(const bh8*)(bw + 4096 + ks * 16), f1);
            f2a = mfma_bf16(a8, *(const bh8*)(bw + 8192 + ks * 16), f2a);
            f3a = mfma_bf16(a8, *(const bh8*)(bw + 12288 + ks * 16), f3a);
        }
    }
    unsigned short* sTB = sX;                     // sX dead since GEMM1
    if (lane < 32) {
        #pragma unroll
        for (int t = 0; t < 4; t++) {
            const fx16& ft = (t == 0) ? f0 : (t == 1) ? f1 : (t == 2) ? f2a : f3a;
            int col = 128 * wid + 32 * t + lane31;
            float bias = Win_b[col];
            sTB[0 * TBS + col] = f2bf(gelu_f(ft[0] + bias));  // reg0 -> row0
            sTB[1 * TBS + col] = f2bf(gelu_f(ft[1] + bias));  // reg1 -> row1
        }
    }
    __syncthreads();

    // ---- FFN-out: [2(pad 32),512] @ Wout^T(128x512) ----
    fx16 o = zv;
    {
        const unsigned short* a = sTB + lane31 * TBS + lk;
        const unsigned short* bw = Woutbf + (32 * wid + lane31) * 512 + lk;
        for (int ks = 0; ks < 32; ks++)
            o = mfma_bf16(*(const bh8*)(a + ks * 16), *(const bh8*)(bw + ks * 16), o);
    }
    if (lane < 32) {
        int col = 32 * wid + lane31;
        float bias = Wout_b[col];
        sM2[col] = o[0] + bias;
        sM2[128 + col] = o[1] + bias;
    }
    __syncthreads();

    // ---- residual + LN2 + mask_V + store ----
    {
        int g = tid >> 7, c = tid & 127;
        sHvX[g * 128 + c] = sHv1[g * 128 + c] + sM2[g * 128 + c];
    }
    __syncthreads();
    if (wid < 2) {
        float x0 = sHvX[wid * 128 + lane], x1 = sHvX[wid * 128 + 64 + lane];
        float s = x0 + x1, q = x0 * x0 + x1 * x1;
        #pragma unroll
        for (int off = 32; off; off >>= 1) { s += __shfl_down(s, off); q += __shfl_down(q, off); }
        if (lane == 0) {
            float mean = s * 0.0078125f;
            sStats[wid * 2] = mean;
            sStats[wid * 2 + 1] = rsqrtf(q * 0.0078125f - mean * mean + 1e-5f);
        }
    }
    __syncthreads();
    {
        int g = tid >> 7, c = tid & 127;
        float y = (sHvX[g * 128 + c] - sStats[g * 2]) * sStats[g * 2 + 1] * g2v[c] + b2v[c];
        y *= mask_V[p0 + g];
        hV_out[(size_t)(p0 + g) * Hn + c] = y;
    }
}

// ---------------------------------------------------------------------------
// Kernel B: edge update (reads updated h_V from d_out), per-edge-row LN.
// ---------------------------------------------------------------------------
__global__ __launch_bounds__(256, 2) void edge_update_mfma(
    const float* __restrict__ hV_new, const float* __restrict__ h_E,
    const int* __restrict__ E_idx,
    const unsigned short* __restrict__ wsbf,
    const float* __restrict__ W11_b, const float* __restrict__ W12_b,
    const float* __restrict__ W13_b,
    const float* __restrict__ g3v, const float* __restrict__ b3v,
    float* __restrict__ hE_out) {
    __shared__ unsigned short sX[64 * XS];   // live to the end (h_E residual segment)
    __shared__ unsigned short sY[64 * YS];

    const int tid = threadIdx.x;
    const int p0 = blockIdx.x * 2;
    const int bB = p0 >> 11;
    const unsigned short* W11bf = wsbf + OFF_W11;
    const unsigned short* W12bf = wsbf + OFF_W12;
    const unsigned short* W13bf = wsbf + OFF_W13;

    for (int i = tid; i < 1920; i += 256) {
        int r = i >> 5, c4 = (i & 31) << 2;
        float4 v = *(const float4*)(h_E + ((size_t)(p0 * Kn + r)) * Hn + c4);
        st_bf4(sX + r * XS + 128 + c4, v);
    }
    for (int i = tid; i < 1920; i += 256) {
        int r = i >> 5, c4 = (i & 31) << 2;
        int idx = E_idx[p0 * Kn + r];
        float4 v = *(const float4*)(hV_new + ((size_t)(bB * NB + idx)) * Hn + c4);
        st_bf4(sX + r * XS + 256 + c4, v);
    }
    for (int i = tid; i < 1920; i += 256) {
        int r = i >> 5, c4 = (i & 31) << 2;
        float4 v = *(const float4*)(hV_new + ((size_t)(p0 + (r >= Kn))) * Hn + c4);
        st_bf4(sX + r * XS + c4, v);
    }
    __syncthreads();

    const int wid = tid >> 6, lane = tid & 63;
    const int mt = wid & 1, np = wid >> 1;
    const int lane31 = lane & 31, lk = (lane >> 5) << 3;
    const int rowBase = 32 * mt;
    const fx16 zv = {};

    fx16 acc0 = zv, acc1 = zv;
    gemm_pair(sX + (rowBase + lane31) * XS + lk,
              W11bf + (64 * np + lane31) * 384 + lk,
              W11bf + (64 * np + 32 + lane31) * 384 + lk, 24, acc0, acc1);
    epi_gelu(acc0, 64 * np,      rowBase, W11_b, sY, lane);
    epi_gelu(acc1, 64 * np + 32, rowBase, W11_b, sY, lane);
    __syncthreads();

    acc0 = zv; acc1 = zv;
    gemm_pair(sY + (rowBase + lane31) * YS + lk,
              W12bf + (64 * np + lane31) * 128 + lk,
              W12bf + (64 * np + 32 + lane31) * 128 + lk, 8, acc0, acc1);
    __syncthreads();
    epi_gelu(acc0, 64 * np,      rowBase, W12_b, sY, lane);
    epi_gelu(acc1, 64 * np + 32, rowBase, W12_b, sY, lane);
    __syncthreads();

    acc0 = zv; acc1 = zv;
    gemm_pair(sY + (rowBase + lane31) * YS + lk,
              W13bf + (64 * np + lane31) * 128 + lk,
              W13bf + (64 * np + 32 + lane31) * 128 + lk, 8, acc0, acc1);
    __syncthreads();
    epi_plain(acc0, 64 * np,      rowBase, W13_b, sY, lane);
    epi_plain(acc1, 64 * np + 32, rowBase, W13_b, sY, lane);
    __syncthreads();

    // per-edge-row LN over E=128: wave handles rows wid, wid+4, ...
    for (int r = wid; r < 60; r += 4) {
        float x0 = bf2f(sX[r * XS + 128 + lane]) + bf2f(sY[r * YS + lane]);
        float x1 = bf2f(sX[r * XS + 192 + lane]) + bf2f(sY[r * YS + 64 + lane]);
        float s = x0 + x1, q = x0 * x0 + x1 * x1;
        #pragma unroll
        for (int off = 32; off; off >>= 1) { s += __shfl_down(s, off); q += __shfl_down(q, off); }
        s = __shfl(s, 0); q = __shfl(q, 0);
        float mean = s * 0.0078125f;
        float rstd = rsqrtf(q * 0.0078125f - mean * mean + 1e-5f);
        float* op = hE_out + ((size_t)(p0 * Kn + r)) * 128;
        op[lane]      = (x0 - mean) * rstd * g3v[lane] + b3v[lane];
        op[lane + 64] = (x1 - mean) * rstd * g3v[lane + 64] + b3v[lane + 64];
    }
}

extern "C" void kernel_launch(void* const* d_in, const int* in_sizes, int n_in,
                              void* d_out, int out_size, void* d_ws, size_t ws_size,
                              hipStream_t stream) {
    const float* h_V         = (const float*)d_in[0];
    const float* h_E         = (const float*)d_in[1];
    const int*   E_idx       = (const int*)  d_in[2];
    const float* mask_V      = (const float*)d_in[3];
    const float* mask_attend = (const float*)d_in[4];
    const float* W1_w  = (const float*)d_in[5];
    const float* W1_b  = (const float*)d_in[6];
    const float* W2_w  = (const float*)d_in[7];
    const float* W2_b  = (const float*)d_in[8];
    const float* W3_w  = (const float*)d_in[9];
    const float* W3_b  = (const float*)d_in[10];
    const float* W11_w = (const float*)d_in[11];
    const float* W11_b = (const float*)d_in[12];
    const float* W12_w = (const float*)d_in[13];
    const float* W12_b = (const float*)d_in[14];
    const float* W13_w = (const float*)d_in[15];
    const float* W13_b = (const float*)d_in[16];
    const float* Win_w  = (const float*)d_in[17];
    const float* Win_b  = (const float*)d_in[18];
    const float* Wout_w = (const float*)d_in[19];
    const float* Wout_b = (const float*)d_in[20];
    const float* g1 = (const float*)d_in[21];
    const float* b1 = (const float*)d_in[22];
    const float* g2 = (const float*)d_in[23];
    const float* b2 = (const float*)d_in[24];
    const float* g3 = (const float*)d_in[25];
    const float* b3 = (const float*)d_in[26];

    float* out    = (float*)d_out;
    float* hV_out = out;                          // [B,N,H]
    float* hE_out = out + (size_t)4 * 2048 * 128; // [B,N,K,E]
    unsigned short* wsbf = (unsigned short*)d_ws;

    prep_weights<<<(W_TOTAL + 255) / 256, 256, 0, stream>>>(
        W1_w, W2_w, W3_w, W11_w, W12_w, W13_w, Win_w, Wout_w, wsbf);

    node_update_mfma<<<4096, 256, 0, stream>>>(
        h_V, h_E, E_idx, mask_V, mask_attend, wsbf,
        W1_b, W2_b, W3_b, Win_b, Wout_b,
        g1, b1, g2, b2, hV_out);

    edge_update_mfma<<<4096, 256, 0, stream>>>(
        hV_out, h_E, E_idx, wsbf,
        W11_b, W12_b, W13_b, g3, b3, hE_out);
}

// Round 3
// 625.253 us; speedup vs baseline: 6.7090x; 1.4160x over previous
//
#include <hip/hip_runtime.h>
#include <math.h>

// Problem constants
#define Kn    30
#define Hn    128
#define NB    2048          // nodes per batch
#define XS2   264           // X row stride (256 + 8 pad): 33 16B-groups (odd) -> conflict-free b128
#define YS    136           // Y row stride (128 + 8 pad): 17 groups (odd)

// ws layout: bf16 weights, then fp32 scratch
#define OFF_W1    0
#define OFF_W2    49152
#define OFF_W3    65536
#define OFF_W11   81920
#define OFF_W12   131072
#define OFF_W13   147456
#define OFF_WIN   163840
#define OFF_WOUT  229376
#define W_TOTAL   294912
// fp32 scratch offsets (in floats, relative to end of weight region)
#define WS_HMID   0
#define WS_S1     1048576
#define WS_S11    2097152

typedef __attribute__((ext_vector_type(8)))  short bh8;
typedef __attribute__((ext_vector_type(4)))  short bh4;
typedef __attribute__((ext_vector_type(16))) float fx16;

__device__ __forceinline__ unsigned short f2bf(float f) {
    unsigned int u = __float_as_uint(f);
    u += 0x7fffu + ((u >> 16) & 1u);        // RNE
    return (unsigned short)(u >> 16);
}
__device__ __forceinline__ float bf2f(unsigned short h) {
    return __uint_as_float(((unsigned int)h) << 16);
}
// tanh-form GELU via v_exp_f32 (|err vs erf-GELU| <~1e-3, cheap: ~8 VALU ops)
__device__ __forceinline__ float gelu_f(float x) {
    float u = 0.7978845608028654f * x * (1.0f + 0.044715f * x * x);
    return x / (1.0f + __expf(-2.0f * u));
}
__device__ __forceinline__ fx16 mfma_bf16(bh8 a, bh8 b, fx16 c) {
    return __builtin_amdgcn_mfma_f32_32x32x16_bf16(a, b, c, 0, 0, 0);
}
__device__ __forceinline__ void st_bf4(unsigned short* dst, float4 v) {
    bh4 t;
    t.x = (short)f2bf(v.x); t.y = (short)f2bf(v.y);
    t.z = (short)f2bf(v.z); t.w = (short)f2bf(v.w);
    *(bh4*)dst = t;                          // ds_write_b64
}

// Fully-unrolled K-loop: one A row-tile (32 rows) x two B n-tiles.
template<int KS>
__device__ __forceinline__ void gemm_pair(const unsigned short* __restrict__ aBase,
                                          const unsigned short* __restrict__ b0,
                                          const unsigned short* __restrict__ b1,
                                          fx16& acc0, fx16& acc1) {
    #pragma unroll
    for (int ks = 0; ks < KS; ks++) {
        bh8 a = *(const bh8*)(aBase + ks * 16);
        acc0 = mfma_bf16(a, *(const bh8*)(b0 + ks * 16), acc0);
        acc1 = mfma_bf16(a, *(const bh8*)(b1 + ks * 16), acc1);
    }
}

// C-layout (verified m74/m101): col = lane&31, row = (reg&3)+8*(reg>>2)+4*(lane>>5)
__device__ __forceinline__ void epi_gelu_s(const fx16& ac, int col, int rowBase,
                                           float bias, const float* __restrict__ sSelf,
                                           unsigned short* __restrict__ dst, int lane) {
    int ro = rowBase + 4 * (lane >> 5);
    #pragma unroll
    for (int r = 0; r < 16; r++) {
        int row = ro + (r & 3) + 8 * (r >> 2);
        float st = sSelf[((row >= Kn) ? 128 : 0) + col];
        dst[row * YS + col] = f2bf(gelu_f(ac[r] + bias + st));
    }
}
__device__ __forceinline__ void epi_gelu(const fx16& ac, int col, int rowBase,
                                         float bias, unsigned short* __restrict__ dst,
                                         int lane) {
    int ro = rowBase + 4 * (lane >> 5);
    #pragma unroll
    for (int r = 0; r < 16; r++) {
        int row = ro + (r & 3) + 8 * (r >> 2);
        dst[row * YS + col] = f2bf(gelu_f(ac[r] + bias));
    }
}
__device__ __forceinline__ void epi_plain(const fx16& ac, int col, int rowBase,
                                          float bias, unsigned short* __restrict__ dst,
                                          int lane) {
    int ro = rowBase + 4 * (lane >> 5);
    #pragma unroll
    for (int r = 0; r < 16; r++) {
        int row = ro + (r & 3) + 8 * (r >> 2);
        dst[row * YS + col] = f2bf(ac[r] + bias);
    }
}

// ---------------------------------------------------------------------------
// prep: fp32 -> bf16 weights into workspace
// ---------------------------------------------------------------------------
__global__ __launch_bounds__(256) void prep_weights(
    const float* __restrict__ W1, const float* __restrict__ W2,
    const float* __restrict__ W3, const float* __restrict__ W11,
    const float* __restrict__ W12, const float* __restrict__ W13,
    const float* __restrict__ Win, const float* __restrict__ Wout,
    unsigned short* __restrict__ wsbf) {
    int i = blockIdx.x * 256 + threadIdx.x;
    if (i >= W_TOTAL) return;
    float v;
    if      (i < OFF_W2)   v = W1[i - OFF_W1];
    else if (i < OFF_W3)   v = W2[i - OFF_W2];
    else if (i < OFF_W11)  v = W3[i - OFF_W3];
    else if (i < OFF_W12)  v = W11[i - OFF_W11];
    else if (i < OFF_W13)  v = W12[i - OFF_W12];
    else if (i < OFF_WIN)  v = W13[i - OFF_W13];
    else if (i < OFF_WOUT) v = Win[i - OFF_WIN];
    else                   v = Wout[i - OFF_WOUT];
    wsbf[i] = f2bf(v);
}

// ---------------------------------------------------------------------------
// self-term for node GEMM1: s1[p] = h_V[p] @ W1self^T  (no bias)
// 256 blocks x 32 rows, 4 waves, each wave one 32-col n-tile.
// ---------------------------------------------------------------------------
__global__ __launch_bounds__(256) void self_gemm(
    const float* __restrict__ hv, const unsigned short* __restrict__ wsbf,
    float* __restrict__ s1) {
    __shared__ __align__(16) unsigned short sA[32 * YS];
    const int tid = threadIdx.x;
    const int p0 = blockIdx.x * 32;
    const unsigned short* W1bf = wsbf + OFF_W1;
    for (int i = tid; i < 1024; i += 256) {
        int r = i >> 5, c4 = (i & 31) << 2;
        float4 v = *(const float4*)(hv + (size_t)(p0 + r) * Hn + c4);
        st_bf4(sA + r * YS + c4, v);
    }
    __syncthreads();
    const int wid = tid >> 6, lane = tid & 63;
    const int lane31 = lane & 31, lk = (lane >> 5) << 3;
    fx16 acc = {};
    const unsigned short* a = sA + lane31 * YS + lk;
    const unsigned short* bw = W1bf + (size_t)(32 * wid + lane31) * 384 + lk; // self cols 0..127
    #pragma unroll
    for (int ks = 0; ks < 8; ks++)
        acc = mfma_bf16(*(const bh8*)(a + ks * 16), *(const bh8*)(bw + ks * 16), acc);
    int col = 32 * wid + lane31;
    #pragma unroll
    for (int r = 0; r < 16; r++) {
        int row = (r & 3) + 8 * (r >> 2) + 4 * (lane >> 5);
        s1[(size_t)(p0 + row) * Hn + col] = acc[r];
    }
}

// ---------------------------------------------------------------------------
// Kernel A: node message MLP + masked mean + residual + LN1 -> hmid (fp32)
// G=2 nodes/block, M=60(pad 64). LDS ~52 KB -> 3 blocks/CU.
// ---------------------------------------------------------------------------
__global__ __launch_bounds__(256, 3) void node_update_mfma(
    const float* __restrict__ h_V, const float* __restrict__ h_E,
    const int* __restrict__ E_idx, const float* __restrict__ mask_attend,
    const unsigned short* __restrict__ wsbf, const float* __restrict__ s1,
    const float* __restrict__ W1_b, const float* __restrict__ W2_b,
    const float* __restrict__ W3_b,
    const float* __restrict__ g1v, const float* __restrict__ b1v,
    float* __restrict__ hmid) {
    __shared__ __align__(16) unsigned short sX[64 * XS2]; // [h_E|nbr]; fp32 scratch after GEMM1
    __shared__ __align__(16) unsigned short sY[64 * YS];
    __shared__ float sS1[256];
    __shared__ float sMask[64];
    __shared__ float sStats[4];

    const int tid = threadIdx.x;
    const int p0 = blockIdx.x * 2;
    const int bB = p0 >> 11;
    const unsigned short* W1bf = wsbf + OFF_W1;
    const unsigned short* W2bf = wsbf + OFF_W2;
    const unsigned short* W3bf = wsbf + OFF_W3;

    // ---- staging ----
    for (int i = tid; i < 1920; i += 256) {          // h_E -> cols 0..127
        int r = i >> 5, c4 = (i & 31) << 2;
        float4 v = *(const float4*)(h_E + ((size_t)(p0 * Kn + r)) * Hn + c4);
        st_bf4(sX + r * XS2 + c4, v);
    }
    for (int i = tid; i < 1920; i += 256) {          // neighbors -> cols 128..255
        int r = i >> 5, c4 = (i & 31) << 2;
        int idx = E_idx[p0 * Kn + r];
        float4 v = *(const float4*)(h_V + ((size_t)(bB * NB + idx)) * Hn + c4);
        st_bf4(sX + r * XS2 + 128 + c4, v);
    }
    for (int i = tid; i < 528; i += 256)             // zero pad rows 60..63
        ((unsigned int*)(sX + 60 * XS2))[i] = 0;
    if (tid < 64) {
        int g = tid >> 5, c4 = (tid & 31) << 2;
        *(float4*)(sS1 + g * 128 + c4) = *(const float4*)(s1 + (size_t)(p0 + g) * Hn + c4);
    }
    if (tid < 60) sMask[tid] = mask_attend[p0 * Kn + tid];
    __syncthreads();

    const int wid = tid >> 6, lane = tid & 63;
    const int mt = wid & 1, np = wid >> 1;
    const int lane31 = lane & 31, lk = (lane >> 5) << 3;
    const int rowBase = 32 * mt;
    const fx16 zv = {};

    // ---- GEMM1: X[64,256] @ W1[:,128:384]^T + s1 + b -> GELU -> Y ----
    fx16 acc0 = zv, acc1 = zv;
    gemm_pair<16>(sX + (rowBase + lane31) * XS2 + lk,
                  W1bf + (64 * np + lane31) * 384 + 128 + lk,
                  W1bf + (64 * np + 32 + lane31) * 384 + 128 + lk, acc0, acc1);
    {
        int c0 = 64 * np + lane31, c1 = c0 + 32;
        epi_gelu_s(acc0, c0, rowBase, W1_b[c0], sS1, sY, lane);
        epi_gelu_s(acc1, c1, rowBase, W1_b[c1], sS1, sY, lane);
    }
    __syncthreads();

    // ---- GEMM2 (in place, sync-guarded) ----
    acc0 = zv; acc1 = zv;
    gemm_pair<8>(sY + (rowBase + lane31) * YS + lk,
                 W2bf + (64 * np + lane31) * 128 + lk,
                 W2bf + (64 * np + 32 + lane31) * 128 + lk, acc0, acc1);
    __syncthreads();
    {
        int c0 = 64 * np + lane31, c1 = c0 + 32;
        epi_gelu(acc0, c0, rowBase, W2_b[c0], sY, lane);
        epi_gelu(acc1, c1, rowBase, W2_b[c1], sY, lane);
    }
    __syncthreads();

    // ---- GEMM3 + masked k-reduction (partials into fp32 scratch over sX) ----
    acc0 = zv; acc1 = zv;
    gemm_pair<8>(sY + (rowBase + lane31) * YS + lk,
                 W3bf + (64 * np + lane31) * 128 + lk,
                 W3bf + (64 * np + 32 + lane31) * 128 + lk, acc0, acc1);
    float* fbuf = (float*)sX;                        // sX dead after GEMM1
    #pragma unroll
    for (int t = 0; t < 2; t++) {
        const fx16& ac = t ? acc1 : acc0;
        int col = 64 * np + 32 * t + lane31;
        float bias = W3_b[col];
        float sA0 = 0.f, sA1 = 0.f;
        #pragma unroll
        for (int r = 0; r < 16; r++) {
            int row = rowBase + (r & 3) + 8 * (r >> 2) + 4 * (lane >> 5);
            if (row < 60) {
                float v = (ac[r] + bias) * sMask[row];
                if (row < Kn) sA0 += v; else sA1 += v;
            }
        }
        sA0 += __shfl_down(sA0, 32);
        sA1 += __shfl_down(sA1, 32);
        if (lane < 32) { fbuf[mt * 256 + col] = sA0; fbuf[mt * 256 + 128 + col] = sA1; }
    }
    __syncthreads();

    // ---- residual + LN1 -> hmid ----
    float* xbuf = fbuf + 512;
    {
        int g = tid >> 7, c = tid & 127;
        float x = h_V[(size_t)(p0 + g) * Hn + c] +
                  (fbuf[g * 128 + c] + fbuf[256 + g * 128 + c]) * (1.0f / 30.0f);
        xbuf[g * 128 + c] = x;
    }
    __syncthreads();
    if (wid < 2) {
        float x0 = xbuf[wid * 128 + lane], x1 = xbuf[wid * 128 + 64 + lane];
        float s = x0 + x1, q = x0 * x0 + x1 * x1;
        #pragma unroll
        for (int off = 32; off; off >>= 1) { s += __shfl_down(s, off); q += __shfl_down(q, off); }
        if (lane == 0) {
            float mean = s * 0.0078125f;
            sStats[wid * 2] = mean;
            sStats[wid * 2 + 1] = rsqrtf(q * 0.0078125f - mean * mean + 1e-5f);
        }
    }
    __syncthreads();
    {
        int g = tid >> 7, c = tid & 127;
        float hv = (xbuf[g * 128 + c] - sStats[g * 2]) * sStats[g * 2 + 1] * g1v[c] + b1v[c];
        hmid[(size_t)(p0 + g) * Hn + c] = hv;
    }
}

// ---------------------------------------------------------------------------
// Kernel B: FFN + LN2 + mask_V -> hV_out, then s11 = hV_out @ W11self^T.
// 256 blocks x 32 rows, full MFMA row utilization, chunked K over hidden=512.
// ---------------------------------------------------------------------------
__global__ __launch_bounds__(256) void ffn_fused(
    const float* __restrict__ hmid, const float* __restrict__ mask_V,
    const unsigned short* __restrict__ wsbf,
    const float* __restrict__ Win_b, const float* __restrict__ Wout_b,
    const float* __restrict__ g2v, const float* __restrict__ b2v,
    float* __restrict__ hV_out, float* __restrict__ s11) {
    __shared__ __align__(16) unsigned short sA[32 * YS];  // hmid bf16
    __shared__ __align__(16) unsigned short sH[32 * YS];  // hidden chunk bf16
    __shared__ __align__(16) float sO[32 * 132];          // FFN-out fp32
    __shared__ __align__(16) unsigned short sV[32 * YS];  // hV_out bf16 for s11

    const int tid = threadIdx.x;
    const int p0 = blockIdx.x * 32;
    const unsigned short* Winbf  = wsbf + OFF_WIN;
    const unsigned short* Woutbf = wsbf + OFF_WOUT;
    const unsigned short* W11bf  = wsbf + OFF_W11;

    for (int i = tid; i < 1024; i += 256) {
        int r = i >> 5, c4 = (i & 31) << 2;
        float4 v = *(const float4*)(hmid + (size_t)(p0 + r) * Hn + c4);
        st_bf4(sA + r * YS + c4, v);
    }
    __syncthreads();

    const int wid = tid >> 6, lane = tid & 63;
    const int lane31 = lane & 31, lk = (lane >> 5) << 3;
    const fx16 zv = {};
    fx16 accO = zv;

    for (int c = 0; c < 4; c++) {
        int hcol = 128 * c + 32 * wid + lane31;
        fx16 t = zv;
        {
            const unsigned short* a  = sA + lane31 * YS + lk;
            const unsigned short* bw = Winbf + (size_t)hcol * 128 + lk;
            #pragma unroll
            for (int ks = 0; ks < 8; ks++)
                t = mfma_bf16(*(const bh8*)(a + ks * 16), *(const bh8*)(bw + ks * 16), t);
        }
        float bias = Win_b[hcol];
        int colL = 32 * wid + lane31;
        #pragma unroll
        for (int r = 0; r < 16; r++) {
            int row = (r & 3) + 8 * (r >> 2) + 4 * (lane >> 5);
            sH[row * YS + colL] = f2bf(gelu_f(t[r] + bias));
        }
        __syncthreads();
        {
            const unsigned short* a  = sH + lane31 * YS + lk;
            const unsigned short* bw = Woutbf + (size_t)(32 * wid + lane31) * 512 + 128 * c + lk;
            #pragma unroll
            for (int ks = 0; ks < 8; ks++)
                accO = mfma_bf16(*(const bh8*)(a + ks * 16), *(const bh8*)(bw + ks * 16), accO);
        }
        __syncthreads();
    }
    {
        int col = 32 * wid + lane31;
        float bias = Wout_b[col];
        #pragma unroll
        for (int r = 0; r < 16; r++) {
            int row = (r & 3) + 8 * (r >> 2) + 4 * (lane >> 5);
            sO[row * 132 + col] = accO[r] + bias;
        }
    }
    __syncthreads();
    for (int r = wid; r < 32; r += 4) {
        float x0 = sO[r * 132 + lane]      + hmid[(size_t)(p0 + r) * Hn + lane];
        float x1 = sO[r * 132 + 64 + lane] + hmid[(size_t)(p0 + r) * Hn + 64 + lane];
        float s = x0 + x1, q = x0 * x0 + x1 * x1;
        #pragma unroll
        for (int off = 32; off; off >>= 1) { s += __shfl_down(s, off); q += __shfl_down(q, off); }
        s = __shfl(s, 0); q = __shfl(q, 0);
        float mean = s * 0.0078125f;
        float rstd = rsqrtf(q * 0.0078125f - mean * mean + 1e-5f);
        float mv = mask_V[p0 + r];
        float y0 = ((x0 - mean) * rstd * g2v[lane]      + b2v[lane])      * mv;
        float y1 = ((x1 - mean) * rstd * g2v[lane + 64] + b2v[lane + 64]) * mv;
        hV_out[(size_t)(p0 + r) * Hn + lane]      = y0;
        hV_out[(size_t)(p0 + r) * Hn + 64 + lane] = y1;
        sV[r * YS + lane]      = f2bf(y0);
        sV[r * YS + 64 + lane] = f2bf(y1);
    }
    __syncthreads();
    {
        int col = 32 * wid + lane31;
        fx16 acc = zv;
        const unsigned short* a  = sV + lane31 * YS + lk;
        const unsigned short* bw = W11bf + (size_t)col * 384 + lk;   // self cols 0..127
        #pragma unroll
        for (int ks = 0; ks < 8; ks++)
            acc = mfma_bf16(*(const bh8*)(a + ks * 16), *(const bh8*)(bw + ks * 16), acc);
        #pragma unroll
        for (int r = 0; r < 16; r++) {
            int row = (r & 3) + 8 * (r >> 2) + 4 * (lane >> 5);
            s11[(size_t)(p0 + row) * Hn + col] = acc[r];
        }
    }
}

// ---------------------------------------------------------------------------
// Kernel C: edge update (reads updated h_V + precomputed s11), per-row LN.
// ---------------------------------------------------------------------------
__global__ __launch_bounds__(256, 3) void edge_update_mfma(
    const float* __restrict__ hV_new, const float* __restrict__ h_E,
    const int* __restrict__ E_idx,
    const unsigned short* __restrict__ wsbf, const float* __restrict__ s11,
    const float* __restrict__ W11_b, const float* __restrict__ W12_b,
    const float* __restrict__ W13_b,
    const float* __restrict__ g3v, const float* __restrict__ b3v,
    float* __restrict__ hE_out) {
    __shared__ __align__(16) unsigned short sX[64 * XS2]; // h_E cols 0..127 live to end
    __shared__ __align__(16) unsigned short sY[64 * YS];
    __shared__ float sS11[256];

    const int tid = threadIdx.x;
    const int p0 = blockIdx.x * 2;
    const int bB = p0 >> 11;
    const unsigned short* W11bf = wsbf + OFF_W11;
    const unsigned short* W12bf = wsbf + OFF_W12;
    const unsigned short* W13bf = wsbf + OFF_W13;

    for (int i = tid; i < 1920; i += 256) {
        int r = i >> 5, c4 = (i & 31) << 2;
        float4 v = *(const float4*)(h_E + ((size_t)(p0 * Kn + r)) * Hn + c4);
        st_bf4(sX + r * XS2 + c4, v);
    }
    for (int i = tid; i < 1920; i += 256) {
        int r = i >> 5, c4 = (i & 31) << 2;
        int idx = E_idx[p0 * Kn + r];
        float4 v = *(const float4*)(hV_new + ((size_t)(bB * NB + idx)) * Hn + c4);
        st_bf4(sX + r * XS2 + 128 + c4, v);
    }
    for (int i = tid; i < 528; i += 256)
        ((unsigned int*)(sX + 60 * XS2))[i] = 0;
    if (tid < 64) {
        int g = tid >> 5, c4 = (tid & 31) << 2;
        *(float4*)(sS11 + g * 128 + c4) = *(const float4*)(s11 + (size_t)(p0 + g) * Hn + c4);
    }
    __syncthreads();

    const int wid = tid >> 6, lane = tid & 63;
    const int mt = wid & 1, np = wid >> 1;
    const int lane31 = lane & 31, lk = (lane >> 5) << 3;
    const int rowBase = 32 * mt;
    const fx16 zv = {};

    fx16 acc0 = zv, acc1 = zv;
    gemm_pair<16>(sX + (rowBase + lane31) * XS2 + lk,
                  W11bf + (64 * np + lane31) * 384 + 128 + lk,
                  W11bf + (64 * np + 32 + lane31) * 384 + 128 + lk, acc0, acc1);
    {
        int c0 = 64 * np + lane31, c1 = c0 + 32;
        epi_gelu_s(acc0, c0, rowBase, W11_b[c0], sS11, sY, lane);
        epi_gelu_s(acc1, c1, rowBase, W11_b[c1], sS11, sY, lane);
    }
    __syncthreads();

    acc0 = zv; acc1 = zv;
    gemm_pair<8>(sY + (rowBase + lane31) * YS + lk,
                 W12bf + (64 * np + lane31) * 128 + lk,
                 W12bf + (64 * np + 32 + lane31) * 128 + lk, acc0, acc1);
    __syncthreads();
    {
        int c0 = 64 * np + lane31, c1 = c0 + 32;
        epi_gelu(acc0, c0, rowBase, W12_b[c0], sY, lane);
        epi_gelu(acc1, c1, rowBase, W12_b[c1], sY, lane);
    }
    __syncthreads();

    acc0 = zv; acc1 = zv;
    gemm_pair<8>(sY + (rowBase + lane31) * YS + lk,
                 W13bf + (64 * np + lane31) * 128 + lk,
                 W13bf + (64 * np + 32 + lane31) * 128 + lk, acc0, acc1);
    __syncthreads();
    {
        int c0 = 64 * np + lane31, c1 = c0 + 32;
        epi_plain(acc0, c0, rowBase, W13_b[c0], sY, lane);
        epi_plain(acc1, c1, rowBase, W13_b[c1], sY, lane);
    }
    __syncthreads();

    // per-edge-row LN over E=128 (residual from bf16 h_E in sX)
    for (int r = wid; r < 60; r += 4) {
        float x0 = bf2f(sX[r * XS2 + lane])      + bf2f(sY[r * YS + lane]);
        float x1 = bf2f(sX[r * XS2 + 64 + lane]) + bf2f(sY[r * YS + 64 + lane]);
        float s = x0 + x1, q = x0 * x0 + x1 * x1;
        #pragma unroll
        for (int off = 32; off; off >>= 1) { s += __shfl_down(s, off); q += __shfl_down(q, off); }
        s = __shfl(s, 0); q = __shfl(q, 0);
        float mean = s * 0.0078125f;
        float rstd = rsqrtf(q * 0.0078125f - mean * mean + 1e-5f);
        float* op = hE_out + ((size_t)(p0 * Kn + r)) * 128;
        op[lane]      = (x0 - mean) * rstd * g3v[lane]      + b3v[lane];
        op[lane + 64] = (x1 - mean) * rstd * g3v[lane + 64] + b3v[lane + 64];
    }
}

extern "C" void kernel_launch(void* const* d_in, const int* in_sizes, int n_in,
                              void* d_out, int out_size, void* d_ws, size_t ws_size,
                              hipStream_t stream) {
    const float* h_V         = (const float*)d_in[0];
    const float* h_E         = (const float*)d_in[1];
    const int*   E_idx       = (const int*)  d_in[2];
    const float* mask_V      = (const float*)d_in[3];
    const float* mask_attend = (const float*)d_in[4];
    const float* W1_w  = (const float*)d_in[5];
    const float* W1_b  = (const float*)d_in[6];
    const float* W2_w  = (const float*)d_in[7];
    const float* W2_b  = (const float*)d_in[8];
    const float* W3_w  = (const float*)d_in[9];
    const float* W3_b  = (const float*)d_in[10];
    const float* W11_w = (const float*)d_in[11];
    const float* W11_b = (const float*)d_in[12];
    const float* W12_w = (const float*)d_in[13];
    const float* W12_b = (const float*)d_in[14];
    const float* W13_w = (const float*)d_in[15];
    const float* W13_b = (const float*)d_in[16];
    const float* Win_w  = (const float*)d_in[17];
    const float* Win_b  = (const float*)d_in[18];
    const float* Wout_w = (const float*)d_in[19];
    const float* Wout_b = (const float*)d_in[20];
    const float* g1 = (const float*)d_in[21];
    const float* b1 = (const float*)d_in[22];
    const float* g2 = (const float*)d_in[23];
    const float* b2 = (const float*)d_in[24];
    const float* g3 = (const float*)d_in[25];
    const float* b3 = (const float*)d_in[26];

    float* out    = (float*)d_out;
    float* hV_out = out;                          // [B,N,H]
    float* hE_out = out + (size_t)4 * 2048 * 128; // [B,N,K,E]
    unsigned short* wsbf = (unsigned short*)d_ws;
    float* wsf  = (float*)(wsbf + W_TOTAL);
    float* hmid = wsf + WS_HMID;
    float* s1   = wsf + WS_S1;
    float* s11  = wsf + WS_S11;

    prep_weights<<<(W_TOTAL + 255) / 256, 256, 0, stream>>>(
        W1_w, W2_w, W3_w, W11_w, W12_w, W13_w, Win_w, Wout_w, wsbf);

    self_gemm<<<256, 256, 0, stream>>>(h_V, wsbf, s1);

    node_update_mfma<<<4096, 256, 0, stream>>>(
        h_V, h_E, E_idx, mask_attend, wsbf, s1,
        W1_b, W2_b, W3_b, g1, b1, hmid);

    ffn_fused<<<256, 256, 0, stream>>>(
        hmid, mask_V, wsbf, Win_b, Wout_b, g2, b2, hV_out, s11);

    edge_update_mfma<<<4096, 256, 0, stream>>>(
        hV_out, h_E, E_idx, wsbf, s11,
        W11_b, W12_b, W13_b, g3, b3, hE_out);
}